// Round 1
// baseline (37.046 us; speedup 1.0000x reference)
//
#include <hip/hip_runtime.h>

// Word2vec SGNS loss: sum over all (pos + neg) pairs of softplus(-dot(u_row, v_row)).
// B=16384, K=20, D=64, EMB=1e6 rows of fp32 (256 B each, 16B-aligned).
// Memory-bound random gather: ~179 MB per call.

constexpr int Bn = 16384;
constexpr int Kn = 20;
constexpr int Dn = 64;
constexpr int NPAIRS = Bn * (Kn + 1);   // 344064

#define BDIM 256
#define NBLOCKS 2048

__global__ __launch_bounds__(BDIM) void w2v_partial(
    const int* __restrict__ pos_u, const int* __restrict__ pos_v,
    const int* __restrict__ neg_u, const int* __restrict__ neg_v,
    const float* __restrict__ u_emb, const float* __restrict__ v_emb,
    float* __restrict__ partials)
{
    const int lane16 = threadIdx.x & 15;
    const int group  = (blockIdx.x * BDIM + threadIdx.x) >> 4;   // global 16-lane group
    const int ngroups = (NBLOCKS * BDIM) >> 4;                   // 32768

    float acc = 0.f;
    for (int p = group; p < NPAIRS; p += ngroups) {
        int iu, iv;
        if (p < Bn) { iu = pos_u[p];      iv = pos_v[p]; }
        else        { iu = neg_u[p - Bn]; iv = neg_v[p - Bn]; }  // neg_[uv] flat [B*K]

        const float4 a = *reinterpret_cast<const float4*>(u_emb + (size_t)iu * Dn + (lane16 << 2));
        const float4 b = *reinterpret_cast<const float4*>(v_emb + (size_t)iv * Dn + (lane16 << 2));
        float s = a.x*b.x + a.y*b.y + a.z*b.z + a.w*b.w;

        // reduce dot across the 16 lanes of this group
        s += __shfl_xor(s, 1);
        s += __shfl_xor(s, 2);
        s += __shfl_xor(s, 4);
        s += __shfl_xor(s, 8);

        if (lane16 == 0) {
            // -log_sigmoid(s) = softplus(-s), numerically stable form
            float y = -s;
            acc += fmaxf(y, 0.f) + log1pf(expf(-fabsf(y)));
        }
    }

    // wave reduce: acc nonzero at lanes 0,16,32,48
    acc += __shfl_xor(acc, 16);
    acc += __shfl_xor(acc, 32);

    __shared__ float red[BDIM / 64];
    if ((threadIdx.x & 63) == 0) red[threadIdx.x >> 6] = acc;
    __syncthreads();
    if (threadIdx.x == 0)
        partials[blockIdx.x] = red[0] + red[1] + red[2] + red[3];
}

__global__ __launch_bounds__(BDIM) void w2v_reduce(
    const float* __restrict__ partials, float* __restrict__ out)
{
    float s = 0.f;
    for (int i = threadIdx.x; i < NBLOCKS; i += BDIM) s += partials[i];
    s += __shfl_xor(s, 1);
    s += __shfl_xor(s, 2);
    s += __shfl_xor(s, 4);
    s += __shfl_xor(s, 8);
    s += __shfl_xor(s, 16);
    s += __shfl_xor(s, 32);
    __shared__ float red[BDIM / 64];
    if ((threadIdx.x & 63) == 0) red[threadIdx.x >> 6] = s;
    __syncthreads();
    if (threadIdx.x == 0) out[0] = red[0] + red[1] + red[2] + red[3];
}

extern "C" void kernel_launch(void* const* d_in, const int* in_sizes, int n_in,
                              void* d_out, int out_size, void* d_ws, size_t ws_size,
                              hipStream_t stream) {
    const int*   pos_u = (const int*)d_in[0];
    const int*   pos_v = (const int*)d_in[1];
    const int*   neg_u = (const int*)d_in[2];
    const int*   neg_v = (const int*)d_in[3];
    const float* u_emb = (const float*)d_in[4];
    const float* v_emb = (const float*)d_in[5];
    float* out = (float*)d_out;
    float* partials = (float*)d_ws;   // NBLOCKS floats = 8 KB

    w2v_partial<<<NBLOCKS, BDIM, 0, stream>>>(pos_u, pos_v, neg_u, neg_v,
                                              u_emb, v_emb, partials);
    w2v_reduce<<<1, BDIM, 0, stream>>>(partials, out);
}